// Round 2
// baseline (291.745 us; speedup 1.0000x reference)
//
#include <hip/hip_runtime.h>

// Shapes fixed by setup_inputs():
#define BB   8
#define CF   256
#define HF   128
#define WF   128
#define HL   512
#define WL   512
#define COLD 16

// Only pixels with pseudo-id >= 1 contribute to the output (class 0 is
// dropped by per_class[1:]). Density ~ (1/21)*(15/16) ~ 4.5% -> sparse gather.
//
// ws layout: [B*HF blocks][32 floats]: [0..16) class sums, [16..32) class counts.

__global__ __launch_bounds__(256) void proto_loss_sparse(
    const float* __restrict__ outputs_old,   // [B, COLD, HL, WL]
    const float* __restrict__ features,      // [B, CF, HF, WF]
    const int*   __restrict__ labels,        // [B, HL, WL]
    const float* __restrict__ prototypes,    // [NCLS, CF], only rows 0..15 used
    float* __restrict__ ws)                  // [B*HF][32]
{
    __shared__ int   plist[WF];   // packed (id<<16)|w of needed pixels
    __shared__ float ssum[16];
    __shared__ int   scnt[16];
    __shared__ int   lcnt;

    const int t   = threadIdx.x;
    const int blk = blockIdx.x;          // 0 .. B*HF-1
    const int b   = blk >> 7;
    const int h   = blk & (HF - 1);

    if (t < 16) { ssum[t] = 0.0f; scnt[t] = 0; }
    if (t == 0) lcnt = 0;
    __syncthreads();

    // Phase 1: pseudo-ids. nearest-down src = (4h, 4w). Only label==0 pixels
    // run the 16-channel argmax; only id>=1 pixels are kept.
    if (t < WF) {
        const int w   = t;
        const int lab = labels[(b * HL + h * 4) * WL + w * 4];
        if (lab == 0) {
            const float* po = outputs_old
                + ((size_t)(b * COLD) * HL + (size_t)(h * 4)) * WL + w * 4;
            float best = po[0];
            int   id   = 0;
            #pragma unroll
            for (int c = 1; c < COLD; ++c) {
                float v = po[(size_t)c * (HL * WL)];
                if (v > best) { best = v; id = c; }   // strict >: first-max wins
            }
            if (id > 0) {
                int pos = atomicAdd(&lcnt, 1);
                plist[pos] = w | (id << 16);
                atomicAdd(&scnt[id], 1);
            }
        }
    }
    __syncthreads();
    const int m = lcnt;

    // Phase 2: one wave per needed pixel; 64 lanes x 4 channels dword-gather,
    // wave shuffle-reduce, bin into LDS.
    const int wave = t >> 6;
    const int lane = t & 63;
    for (int p = wave; p < m; p += 4) {
        const int e  = plist[p];
        const int w  = e & 0xffff;
        const int id = e >> 16;
        const float* fb = features + ((size_t)(b * CF) * HF + h) * WF + w;
        const float* pr = prototypes + id * CF;   // L1-resident (21 KB total)
        float acc = 0.0f;
        #pragma unroll
        for (int k = 0; k < 4; ++k) {
            const int c = lane + 64 * k;
            const float d = fb[(size_t)c * (HF * WF)] - pr[c];
            acc += d * d;
        }
        #pragma unroll
        for (int off = 32; off > 0; off >>= 1)
            acc += __shfl_xor(acc, off, 64);
        if (lane == 0)
            atomicAdd(&ssum[id], acc * (1.0f / CF));
    }
    __syncthreads();

    // Per-block partials -> disjoint ws slots (no global atomics, no memset)
    if (t < 16) {
        ws[blk * 32 + t]      = ssum[t];
        ws[blk * 32 + 16 + t] = (float)scnt[t];
    }
}

__global__ __launch_bounds__(256) void proto_loss_final(
    const float* __restrict__ ws,
    const int*   __restrict__ classes_old,
    const int*   __restrict__ inc_step,
    float* __restrict__ out)
{
    __shared__ float red[8 * 32];
    const int t   = threadIdx.x;
    const int s   = t & 31;   // slot 0..31
    const int grp = t >> 5;   // 0..7
    float acc = 0.0f;
    for (int i = grp; i < BB * HF; i += 8)
        acc += ws[i * 32 + s];
    red[grp * 32 + s] = acc;
    __syncthreads();
    if (t == 0) {
        float r = 0.0f;
        if (*inc_step != 0) {
            int K = *classes_old;
            if (K > 16) K = 16;
            for (int id = 1; id < K; ++id) {
                float sum = 0.0f, cnt = 0.0f;
                for (int g = 0; g < 8; ++g) {
                    sum += red[g * 32 + id];
                    cnt += red[g * 32 + 16 + id];
                }
                if (cnt > 0.0f) r += sum / cnt;
            }
        }
        out[0] = r;
    }
}

extern "C" void kernel_launch(void* const* d_in, const int* in_sizes, int n_in,
                              void* d_out, int out_size, void* d_ws, size_t ws_size,
                              hipStream_t stream)
{
    const float* outputs_old = (const float*)d_in[1];
    const float* features    = (const float*)d_in[2];
    const int*   labels      = (const int*)d_in[4];
    const float* prototypes  = (const float*)d_in[5];
    const int*   classes_old = (const int*)d_in[6];
    const int*   inc_step    = (const int*)d_in[7];

    float* ws = (float*)d_ws;   // B*HF*32 floats = 128 KB

    proto_loss_sparse<<<dim3(BB * HF), dim3(256), 0, stream>>>(
        outputs_old, features, labels, prototypes, ws);
    proto_loss_final<<<dim3(1), dim3(256), 0, stream>>>(
        ws, classes_old, inc_step, (float*)d_out);
}